// Round 1
// baseline (93.816 us; speedup 1.0000x reference)
//
#include <hip/hip_runtime.h>
#include <cfloat>
#include <stdint.h>

// Match XLA-CPU f32 arithmetic exactly: no implicit contraction anywhere;
// FMA only where written explicitly (Eigen-gemm-style cross product).
#pragma clang fp contract(off)

#define TILE 1024

__device__ __forceinline__ uint32_t monotone_key(float f) {
    uint32_t u = __float_as_uint(f);
    // map float bits -> monotonically increasing unsigned
    return (u & 0x80000000u) ? ~u : (u | 0x80000000u);
}

__global__ void __launch_bounds__(256) argmin_kernel(
        const float* __restrict__ mesh, const float* __restrict__ recv,
        unsigned long long* __restrict__ ws, int L, int B, int ntiles) {
    __shared__ float4 tile[TILE];
    __shared__ unsigned long long red[4][64];

    const int tid  = threadIdx.x;
    const int lane = tid & 63;
    const int slot = tid >> 6;   // wave id within block, 0..3

    float rx = 0.f, ry = 0.f, rz = 0.f, rsq = 0.f;
    if (lane < B) {
        rx = recv[lane * 3 + 0];
        ry = recv[lane * 3 + 1];
        rz = recv[lane * 3 + 2];
        rsq = (rx * rx + ry * ry) + rz * rz;   // no FMA (pragma)
    }

    float best = FLT_MAX;
    int   bidx = 0x7fffffff;

    for (int t = blockIdx.x; t < ntiles; t += gridDim.x) {
        const int base = t * TILE;
        __syncthreads();   // protect tile[] from previous iteration's readers
        // stage 1024 points: (x, y, z, m_sq) per point
        for (int j = 0; j < 4; ++j) {
            const int p = tid + 256 * j;
            const int g = base + p;
            float x = 0.f, y = 0.f, z = 0.f, msq;
            if (g < L) {
                x = mesh[(size_t)g * 3 + 0];
                y = mesh[(size_t)g * 3 + 1];
                z = mesh[(size_t)g * 3 + 2];
                msq = (x * x + y * y) + z * z;   // no FMA: matches jnp.sum(m*m)
            } else {
                msq = FLT_MAX;                   // d2 huge, never selected
            }
            tile[p] = make_float4(x, y, z, msq);
        }
        __syncthreads();

        const int pbase = slot * 256;
        #pragma unroll 8
        for (int j = 0; j < 256; ++j) {
            const float4 m = tile[pbase + j];    // all 64 lanes same addr: broadcast
            // Eigen gemm K-ascending FMA: fma(rz,mz, fma(ry,my, rx*mx))
            float cross = fmaf(rz, m.z, fmaf(ry, m.y, rx * m.x));
            // m_sq - 2*cross is correctly rounded either way since 2*cross exact
            float d2 = fmaf(-2.0f, cross, m.w) + rsq;
            const int gidx = base + pbase + j;
            if (d2 < best) { best = d2; bidx = gidx; }  // strict <: first-idx tie-break
        }
    }

    // block-level reduce across the 4 wave-slots, then one atomic per receiver
    unsigned long long key =
        ((unsigned long long)monotone_key(best) << 32) | (unsigned int)bidx;
    red[slot][lane] = key;
    __syncthreads();
    if (slot == 0 && lane < B) {
        unsigned long long k = red[0][lane];
        unsigned long long k1 = red[1][lane]; if (k1 < k) k = k1;
        unsigned long long k2 = red[2][lane]; if (k2 < k) k = k2;
        unsigned long long k3 = red[3][lane]; if (k3 < k) k = k3;
        atomicMin(&ws[lane], k);
    }
}

// (L,3) -> (L,4) with one-hot column zeroed; float4-vectorized, 4 points/thread
__global__ void __launch_bounds__(256) expand_kernel(
        const float* __restrict__ mesh, float* __restrict__ out, int L) {
    const int t = blockIdx.x * blockDim.x + threadIdx.x;   // handles points 4t..4t+3
    const int p0 = t * 4;
    if (p0 >= L) return;
    const float4* __restrict__ m4 = (const float4*)mesh;
    float4* __restrict__ o4 = (float4*)out;
    if (p0 + 3 < L) {
        const float4 a = m4[(size_t)t * 3 + 0];
        const float4 b = m4[(size_t)t * 3 + 1];
        const float4 c = m4[(size_t)t * 3 + 2];
        o4[(size_t)t * 4 + 0] = make_float4(a.x, a.y, a.z, 0.f);
        o4[(size_t)t * 4 + 1] = make_float4(a.w, b.x, b.y, 0.f);
        o4[(size_t)t * 4 + 2] = make_float4(b.z, b.w, c.x, 0.f);
        o4[(size_t)t * 4 + 3] = make_float4(c.y, c.z, c.w, 0.f);
    } else {
        for (int p = p0; p < L; ++p) {
            out[(size_t)p * 4 + 0] = mesh[(size_t)p * 3 + 0];
            out[(size_t)p * 4 + 1] = mesh[(size_t)p * 3 + 1];
            out[(size_t)p * 4 + 2] = mesh[(size_t)p * 3 + 2];
            out[(size_t)p * 4 + 3] = 0.f;
        }
    }
}

// scatter one-hot 1.0s and emit closest_points
__global__ void finalize_kernel(
        const float* __restrict__ mesh, const unsigned long long* __restrict__ ws,
        float* __restrict__ out, int L, int B) {
    const int r = threadIdx.x;
    if (r >= B) return;
    const int idx = (int)(ws[r] & 0xFFFFFFFFull);
    out[(size_t)idx * 4 + 3] = 1.0f;
    float* cp = out + (size_t)L * 4 + (size_t)r * 3;
    cp[0] = mesh[(size_t)idx * 3 + 0];
    cp[1] = mesh[(size_t)idx * 3 + 1];
    cp[2] = mesh[(size_t)idx * 3 + 2];
}

extern "C" void kernel_launch(void* const* d_in, const int* in_sizes, int n_in,
                              void* d_out, int out_size, void* d_ws, size_t ws_size,
                              hipStream_t stream) {
    const float* mesh = (const float*)d_in[0];
    const float* recv = (const float*)d_in[1];
    float* out = (float*)d_out;
    const int L = in_sizes[0] / 3;
    const int B = in_sizes[1] / 3;   // 64
    unsigned long long* ws = (unsigned long long*)d_ws;

    // init per-receiver packed (key|idx) mins to max
    hipMemsetAsync(ws, 0xFF, (size_t)B * sizeof(unsigned long long), stream);

    const int ntiles = (L + TILE - 1) / TILE;
    const int nblk   = ntiles < 1024 ? ntiles : 1024;
    argmin_kernel<<<nblk, 256, 0, stream>>>(mesh, recv, ws, L, B, ntiles);

    const int nt4 = (L + 3) / 4;
    expand_kernel<<<(nt4 + 255) / 256, 256, 0, stream>>>(mesh, out, L);

    finalize_kernel<<<1, 64, 0, stream>>>(mesh, ws, out, L, B);
}